// Round 13
// baseline (598.506 us; speedup 1.0000x reference)
//
#include <hip/hip_runtime.h>

#define NN 400000
#define NE 800000
#define NG 16384

typedef short bf16x8 __attribute__((ext_vector_type(8)));
typedef float f32x4 __attribute__((ext_vector_type(4)));
typedef unsigned short u16x8 __attribute__((ext_vector_type(8)));

static inline int cdiv(int a, int b) { return (a + b - 1) / b; }

__device__ inline unsigned short bf16_rne(float v) {
    unsigned u = __float_as_uint(v);
    unsigned r = u + 0x7FFFu + ((u >> 16) & 1u);
    return (unsigned short)(r >> 16);
}
__device__ inline float bf16_to_f(unsigned short h) {
    return __uint_as_float(((unsigned)h) << 16);
}
__device__ inline void split2(float v, unsigned short& hi, unsigned short& lo) {
    hi = bf16_rne(v);
    lo = bf16_rne(v - bf16_to_f(hi));
}

__global__ __launch_bounds__(256) void fill_kernel(float* __restrict__ p, float v, int n) {
    int i = blockIdx.x * blockDim.x + threadIdx.x;
    if (i < n) p[i] = v;
}

__global__ __launch_bounds__(256) void fill_int_kernel(int* __restrict__ p, int v, int n) {
    int i = blockIdx.x * blockDim.x + threadIdx.x;
    if (i < n) p[i] = v;
}

__global__ __launch_bounds__(256) void hist_kernel(const int* __restrict__ dst,
                                                   int* __restrict__ deg, int E) {
    int e = blockIdx.x * blockDim.x + threadIdx.x;
    if (e < E) atomicAdd(&deg[dst[e]], 1);
}

__global__ __launch_bounds__(256) void disq_kernel(const int* __restrict__ deg,
                                                   float* __restrict__ disq, int n) {
    int i = blockIdx.x * blockDim.x + threadIdx.x;
    if (i < n) disq[i] = rsqrtf(1.0f + (float)deg[i]);
}

// ---- 3-pass exclusive scan ----
#define SCAN_TPB 256
#define SCAN_EPT 8
#define SCAN_BE (SCAN_TPB * SCAN_EPT)

__global__ __launch_bounds__(SCAN_TPB) void scan_a_kernel(const int* __restrict__ in,
                                                          int* __restrict__ out,
                                                          int* __restrict__ partials, int n) {
    __shared__ int sums[SCAN_TPB];
    const int tid = threadIdx.x;
    int base = blockIdx.x * SCAN_BE + tid * SCAN_EPT;
    int v[SCAN_EPT];
    int s = 0;
#pragma unroll
    for (int i = 0; i < SCAN_EPT; ++i) {
        int idx = base + i;
        int x = (idx < n) ? in[idx] : 0;
        v[i] = s;
        s += x;
    }
    sums[tid] = s;
    __syncthreads();
    for (int off = 1; off < SCAN_TPB; off <<= 1) {
        int t = (tid >= off) ? sums[tid - off] : 0;
        __syncthreads();
        sums[tid] += t;
        __syncthreads();
    }
    int toff = (tid == 0) ? 0 : sums[tid - 1];
#pragma unroll
    for (int i = 0; i < SCAN_EPT; ++i) {
        int idx = base + i;
        if (idx < n) out[idx] = toff + v[i];
    }
    if (tid == SCAN_TPB - 1) partials[blockIdx.x] = sums[SCAN_TPB - 1];
}

__global__ void scan_b_kernel(int* __restrict__ partials, int nb) {
    if (blockIdx.x == 0 && threadIdx.x == 0) {
        int s = 0;
        for (int i = 0; i < nb; ++i) { int x = partials[i]; partials[i] = s; s += x; }
    }
}

__global__ __launch_bounds__(256) void scan_c_kernel(int* __restrict__ out,
                                                     const int* __restrict__ partials, int n) {
    int idx = blockIdx.x * blockDim.x + threadIdx.x;
    if (idx < n) out[idx] += partials[idx / SCAN_BE];
}

// ---- CSR fill: entry = {src, norm_bits} packed ----
__global__ __launch_bounds__(256) void csr_fill_kernel(const int* __restrict__ src,
                                                       const int* __restrict__ dst,
                                                       const int* __restrict__ rowptr,
                                                       int* __restrict__ cnt,
                                                       const float* __restrict__ disq,
                                                       int2* __restrict__ csr_ent, int E) {
    int e = blockIdx.x * blockDim.x + threadIdx.x;
    if (e >= E) return;
    int d = dst[e], s = src[e];
    int pos = rowptr[d] + atomicAdd(&cnt[d], 1);
    csr_ent[pos] = make_int2(s, __float_as_int(disq[s] * disq[d]));
}

// ---- weight prep: 128x128 slice (k0.., n0..) of W[Ktot][Ntot] fp32
//      -> transposed, split, XOR-swizzled planes ----
__global__ __launch_bounds__(256) void prep_w_kernel(const float* __restrict__ W,
                                                     int Ktot, int Ntot, int k0, int n0,
                                                     unsigned short* __restrict__ planeHi,
                                                     unsigned short* __restrict__ planeLo) {
    int i = blockIdx.x * blockDim.x + threadIdx.x;
    if (i >= 128 * 128) return;
    int n = i >> 7, k = i & 127;
    int gk = k0 + k, gn = n0 + n;
    float v = (gk < Ktot && gn < Ntot) ? W[(size_t)gk * Ntot + gn] : 0.0f;
    unsigned short hi, lo;
    split2(v, hi, lo);
    int elem = (n * 256 + ((2 * k) ^ ((n & 7) << 4))) >> 1;
    planeHi[elem] = hi;
    planeLo[elem] = lo;
}

// ---- x convert: [NN][78] fp32 -> bf16 hi-only [NN][96] (zero pad) ----
// int32 math, 4 elems/thread, ushort4 stores.
__global__ __launch_bounds__(256) void xconv_kernel(const float* __restrict__ x,
                                                    unsigned short* __restrict__ xbf) {
    int t = blockIdx.x * blockDim.x + threadIdx.x;
    if (t >= NN * 24) return;
    int node = t / 24;              // int32 magic-mul
    int q = (t - node * 24) * 4;    // 0,4,...,92
    const float* xp = x + (size_t)node * 78;
    ushort4 o;
    o.x = bf16_rne((q + 0 < 78) ? xp[q + 0] : 0.0f);
    o.y = bf16_rne((q + 1 < 78) ? xp[q + 1] : 0.0f);
    o.z = bf16_rne((q + 2 < 78) ? xp[q + 2] : 0.0f);
    o.w = bf16_rne((q + 3 < 78) ? xp[q + 3] : 0.0f);
    *reinterpret_cast<ushort4*>(xbf + (size_t)node * 96 + q) = o;
}

// ---- fp32 -> bf16 vector convert ----
__global__ __launch_bounds__(256) void f2bf_kernel(const float* __restrict__ in,
                                                   unsigned short* __restrict__ o, int n4) {
    int i = blockIdx.x * blockDim.x + threadIdx.x;
    if (i >= n4) return;
    float4 v = *reinterpret_cast<const float4*>(in + i * 4);
    ushort4 u;
    u.x = bf16_rne(v.x); u.y = bf16_rne(v.y); u.z = bf16_rne(v.z); u.w = bf16_rne(v.w);
    *reinterpret_cast<ushort4*>(o + i * 4) = u;
}

// ---- CSR gather over bf16 activations -> bf16 hi-only agg ----
// 16 lanes/node, ushort8 (16B) per lane -> 4 independent node chains per wave.
template <int STRIDE>
__global__ __launch_bounds__(256) void gather_kernel(const unsigned short* __restrict__ act,
                                                     const int* __restrict__ rowptr,
                                                     const int* __restrict__ deg,
                                                     const int2* __restrict__ csr_ent,
                                                     const float* __restrict__ disq,
                                                     unsigned short* __restrict__ aggHi, int n) {
    int t = blockIdx.x * blockDim.x + threadIdx.x;
    if (t >= n * 16) return;
    int node = t >> 4, q = (t & 15) * 8;
    const bool live = q < STRIDE;
    const int qc = live ? q : 0;
    int beg = rowptr[node];
    int d = deg[node];
    float si = disq[node];
    float s2 = si * si;
    u16x8 su = *reinterpret_cast<const u16x8*>(act + (size_t)node * STRIDE + qc);
    float acc[8];
#pragma unroll
    for (int i = 0; i < 8; ++i) acc[i] = bf16_to_f(su[i]) * s2;
    if (d > 0) {
        int lim = d - 1;
        int2 e[6];
#pragma unroll
        for (int j = 0; j < 6; ++j) e[j] = csr_ent[beg + (j < lim ? j : lim)];
        u16x8 u[6];
        float nr[6];
#pragma unroll
        for (int j = 0; j < 6; ++j) {
            u[j] = *reinterpret_cast<const u16x8*>(act + (size_t)e[j].x * STRIDE + qc);
            nr[j] = (j < d) ? __int_as_float(e[j].y) : 0.0f;
        }
#pragma unroll
        for (int j = 0; j < 6; ++j)
#pragma unroll
            for (int i = 0; i < 8; ++i) acc[i] = fmaf(bf16_to_f(u[j][i]), nr[j], acc[i]);
        for (int j = 6; j < d; ++j) {
            int2 ee = csr_ent[beg + j];
            float nn = __int_as_float(ee.y);
            u16x8 uu = *reinterpret_cast<const u16x8*>(act + (size_t)ee.x * STRIDE + qc);
#pragma unroll
            for (int i = 0; i < 8; ++i) acc[i] = fmaf(bf16_to_f(uu[i]), nn, acc[i]);
        }
    }
    if (live) {
        u16x8 h8;
#pragma unroll
        for (int i = 0; i < 8; ++i) h8[i] = bf16_rne(acc[i]);
        *reinterpret_cast<u16x8*>(aggHi + (size_t)node * STRIDE + q) = h8;
    }
}

// ---- bf16 MFMA GEMM, split weights (Whi+Wlo), 3 epilogue modes ----
// MODE 0: bf16 out = relu(acc + bias), row stride ostride, col offset ocol
// MODE 1: fp32 partial out (no bias/relu), stride 128
// MODE 2: fp32 out = relu(acc + partial + bias), stride 128
template <int NKC, int AS, int MODE>
__global__ __launch_bounds__(256) void gemm_mfma_kernel(const unsigned short* __restrict__ A,
                                                        const unsigned short* __restrict__ WT,
                                                        const float* __restrict__ bias,
                                                        unsigned short* __restrict__ actout,
                                                        float* __restrict__ f32out,
                                                        const float* __restrict__ partial,
                                                        int M, int a_k0, int ostride, int ocol) {
    __shared__ unsigned short lds[2 * 128 * 128];
    const int tid = threadIdx.x;
    {
        const unsigned* s = reinterpret_cast<const unsigned*>(WT);
        unsigned* d = reinterpret_cast<unsigned*>(lds);
#pragma unroll
        for (int i = 0; i < 64; ++i) d[tid + 256 * i] = s[tid + 256 * i];
    }
    __syncthreads();

    const int w = tid >> 6, lane = tid & 63;
    const int m = lane & 15, kb = lane >> 4;
    const char* ldsHiB = reinterpret_cast<const char*>(lds);
    const char* ldsLoB = ldsHiB + 128 * 256;

    float bcol[8];
    if (MODE != 1) {
#pragma unroll
        for (int ct = 0; ct < 8; ++ct) bcol[ct] = bias[ct * 16 + m];
    }

    const int RT = 4;
    for (int rt = 0; rt < RT; ++rt) {
        int row0 = (blockIdx.x * RT + rt) * 64;
        if (row0 >= M) return;
        int arow = row0 + w * 16 + m;

        bf16x8 ah[NKC];
#pragma unroll
        for (int kc = 0; kc < NKC; ++kc)
            ah[kc] = *reinterpret_cast<const bf16x8*>(A + (size_t)arow * AS + a_k0 + kc * 32 + kb * 8);

        f32x4 acc[8];
#pragma unroll
        for (int ct = 0; ct < 8; ++ct)
#pragma unroll
            for (int r = 0; r < 4; ++r) acc[ct][r] = 0.0f;

#pragma unroll
        for (int ct = 0; ct < 8; ++ct) {
            int n = ct * 16 + m;
            int swz = (n & 7) << 4;
            int rowb = n * 256;
#pragma unroll
            for (int kc = 0; kc < NKC; ++kc) {
                int bb = rowb + ((kc * 64 + kb * 16) ^ swz);
                bf16x8 bh = *reinterpret_cast<const bf16x8*>(ldsHiB + bb);
                bf16x8 bl = *reinterpret_cast<const bf16x8*>(ldsLoB + bb);
                acc[ct] = __builtin_amdgcn_mfma_f32_16x16x32_bf16(ah[kc], bh, acc[ct], 0, 0, 0);
                acc[ct] = __builtin_amdgcn_mfma_f32_16x16x32_bf16(ah[kc], bl, acc[ct], 0, 0, 0);
            }
        }

        // C/D: col = ct*16 + (lane&15), row = (lane>>4)*4 + r   [m89]
        if (MODE == 0) {
            unsigned short* ap = actout + (size_t)(row0 + w * 16) * ostride + ocol;
#pragma unroll
            for (int ct = 0; ct < 8; ++ct)
#pragma unroll
                for (int r = 0; r < 4; ++r) {
                    float v = fmaxf(acc[ct][r] + bcol[ct], 0.0f);
                    ap[(size_t)(kb * 4 + r) * ostride + ct * 16 + m] = bf16_rne(v);
                }
        } else if (MODE == 1) {
            float* fp = f32out + (size_t)(row0 + w * 16) * 128;
#pragma unroll
            for (int ct = 0; ct < 8; ++ct)
#pragma unroll
                for (int r = 0; r < 4; ++r)
                    fp[(size_t)(kb * 4 + r) * 128 + ct * 16 + m] = acc[ct][r];
        } else {
            const float* pp = partial + (size_t)(row0 + w * 16) * 128;
            float* fp = f32out + (size_t)(row0 + w * 16) * 128;
#pragma unroll
            for (int ct = 0; ct < 8; ++ct)
#pragma unroll
                for (int r = 0; r < 4; ++r) {
                    size_t idx = (size_t)(kb * 4 + r) * 128 + ct * 16 + m;
                    float v = fmaxf(acc[ct][r] + pp[idx] + bcol[ct], 0.0f);
                    fp[idx] = v;
                }
        }
    }
}

// batch sorted: pre-reduce runs of 8 nodes, flush on boundary. reads bf16 act.
__global__ __launch_bounds__(256) void pool_kernel(const unsigned short* __restrict__ act,
                                                   const int* __restrict__ batch,
                                                   int* __restrict__ pooled, int n) {
    int t = blockIdx.x * blockDim.x + threadIdx.x;
    int d = t & 127;
    int n0 = (t >> 7) * 8;
    if (n0 >= n) return;
    int cur = batch[n0];
    float m = fmaxf(bf16_to_f(act[(size_t)n0 * 128 + d]), 0.f);
    for (int i = 1; i < 8 && (n0 + i) < n; ++i) {
        int b = batch[n0 + i];
        float v = fmaxf(bf16_to_f(act[(size_t)(n0 + i) * 128 + d]), 0.f);
        if (b == cur) {
            m = fmaxf(m, v);
        } else {
            atomicMax(&pooled[cur * 128 + d], __float_as_int(m));
            cur = b;
            m = v;
        }
    }
    atomicMax(&pooled[cur * 128 + d], __float_as_int(m));
}

extern "C" void kernel_launch(void* const* d_in, const int* in_sizes, int n_in,
                              void* d_out, int out_size, void* d_ws, size_t ws_size,
                              hipStream_t stream) {
    const float* x    = (const float*)d_in[0];
    const int*   edge = (const int*)d_in[1];
    const int*   batch= (const int*)d_in[2];
    const float* gW0  = (const float*)d_in[4];
    const float* gb0  = (const float*)d_in[5];
    const float* gW1  = (const float*)d_in[6];
    const float* gb1  = (const float*)d_in[7];
    const float* gW2  = (const float*)d_in[8];
    const float* gb2  = (const float*)d_in[9];
    const float* fW0  = (const float*)d_in[10];
    const float* fb0  = (const float*)d_in[11];
    const float* fW1  = (const float*)d_in[12];
    const float* fb1  = (const float*)d_in[13];
    float* out = (float*)d_out;

    unsigned short* actB  = (unsigned short*)d_ws;            // NN*128 bf16 (aliases xbf NN*96)
    unsigned short* aggHi = actB + (size_t)NN * 128;          // NN*128 bf16
    float* disq   = (float*)(aggHi + (size_t)NN * 128);       // NN f32
    float* pooled = disq + NN;                                // NG*128 f32 (also FF1 partial)
    unsigned short* pooledbf = (unsigned short*)(pooled + (size_t)NG * 128);  // NG*128
    unsigned short* ffhbf    = pooledbf + (size_t)NG * 128;   // NG*256
    int*   deg    = (int*)(ffhbf + (size_t)NG * 256);         // NN
    int*   rowptr = deg + NN;                                 // NN
    int2*  csr_ent = (int2*)(rowptr + NN);                    // NE
    unsigned short* wt0  = (unsigned short*)(csr_ent + NE);   // 2*128*128 each
    unsigned short* wt1  = wt0 + 2 * 128 * 128;
    unsigned short* wt2  = wt1 + 2 * 128 * 128;
    unsigned short* wtF0a = wt2 + 2 * 128 * 128;
    unsigned short* wtF0b = wtF0a + 2 * 128 * 128;
    unsigned short* wtF1a = wtF0b + 2 * 128 * 128;
    unsigned short* wtF1b = wtF1a + 2 * 128 * 128;
    int* partials = (int*)(wtF1b + 2 * 128 * 128);            // ~200 ints
    int* cnt = (int*)pooled;                                  // dead before pool init
    unsigned short* xbf = actB;                               // [NN,96]; dead after gather0

    const int* src = edge;
    const int* dst = edge + NE;

    // ---- degree + disq + CSR build + weight prep + x convert ----
    fill_int_kernel<<<cdiv(NN, 256), 256, 0, stream>>>(deg, 0, NN);
    fill_int_kernel<<<cdiv(NN, 256), 256, 0, stream>>>(cnt, 0, NN);
    hist_kernel<<<cdiv(NE, 256), 256, 0, stream>>>(dst, deg, NE);
    disq_kernel<<<cdiv(NN, 256), 256, 0, stream>>>(deg, disq, NN);
    int nsb = cdiv(NN, SCAN_BE);
    scan_a_kernel<<<nsb, SCAN_TPB, 0, stream>>>(deg, rowptr, partials, NN);
    scan_b_kernel<<<1, 64, 0, stream>>>(partials, nsb);
    scan_c_kernel<<<cdiv(NN, 256), 256, 0, stream>>>(rowptr, partials, NN);
    csr_fill_kernel<<<cdiv(NE, 256), 256, 0, stream>>>(src, dst, rowptr, cnt, disq,
                                                       csr_ent, NE);
    prep_w_kernel<<<64, 256, 0, stream>>>(gW0, 78, 128, 0, 0, wt0, wt0 + 128 * 128);
    prep_w_kernel<<<64, 256, 0, stream>>>(gW1, 128, 128, 0, 0, wt1, wt1 + 128 * 128);
    prep_w_kernel<<<64, 256, 0, stream>>>(gW2, 128, 128, 0, 0, wt2, wt2 + 128 * 128);
    prep_w_kernel<<<64, 256, 0, stream>>>(fW0, 128, 256, 0, 0,   wtF0a, wtF0a + 128 * 128);
    prep_w_kernel<<<64, 256, 0, stream>>>(fW0, 128, 256, 0, 128, wtF0b, wtF0b + 128 * 128);
    prep_w_kernel<<<64, 256, 0, stream>>>(fW1, 256, 128, 0, 0,   wtF1a, wtF1a + 128 * 128);
    prep_w_kernel<<<64, 256, 0, stream>>>(fW1, 256, 128, 128, 0, wtF1b, wtF1b + 128 * 128);
    xconv_kernel<<<cdiv(NN * 24, 256), 256, 0, stream>>>(x, xbf);

    const int gemm_blocks = cdiv(NN / 64, 4);
    const int gather_blocks = cdiv(NN * 16, 256);
    const int ff_blocks = NG / 256;

    // ---- layer 0: agg = A_hat x ; act = relu(agg@W0 + b0) ----
    gather_kernel<96><<<gather_blocks, 256, 0, stream>>>(xbf, rowptr, deg, csr_ent, disq,
                                                         aggHi, NN);
    gemm_mfma_kernel<3, 96, 0><<<gemm_blocks, 256, 0, stream>>>(
        aggHi, wt0, gb0, actB, nullptr, nullptr, NN, 0, 128, 0);
    // ---- layer 1 ----
    gather_kernel<128><<<gather_blocks, 256, 0, stream>>>(actB, rowptr, deg, csr_ent, disq,
                                                          aggHi, NN);
    gemm_mfma_kernel<4, 128, 0><<<gemm_blocks, 256, 0, stream>>>(
        aggHi, wt1, gb1, actB, nullptr, nullptr, NN, 0, 128, 0);
    // ---- layer 2 ----
    gather_kernel<128><<<gather_blocks, 256, 0, stream>>>(actB, rowptr, deg, csr_ent, disq,
                                                          aggHi, NN);
    gemm_mfma_kernel<4, 128, 0><<<gemm_blocks, 256, 0, stream>>>(
        aggHi, wt2, gb2, actB, nullptr, nullptr, NN, 0, 128, 0);

    // ---- global max pool ----
    fill_kernel<<<cdiv(NG * 128, 256), 256, 0, stream>>>(pooled, 0.0f, NG * 128);
    pool_kernel<<<cdiv(cdiv(NN, 8) * 128, 256), 256, 0, stream>>>(actB, batch, (int*)pooled, NN);
    f2bf_kernel<<<cdiv(NG * 32, 256), 256, 0, stream>>>(pooled, pooledbf, NG * 32);

    // ---- FF head (MFMA) ----
    gemm_mfma_kernel<4, 128, 0><<<ff_blocks, 256, 0, stream>>>(
        pooledbf, wtF0a, fb0, ffhbf, nullptr, nullptr, NG, 0, 256, 0);
    gemm_mfma_kernel<4, 128, 0><<<ff_blocks, 256, 0, stream>>>(
        pooledbf, wtF0b, fb0 + 128, ffhbf, nullptr, nullptr, NG, 0, 256, 128);
    gemm_mfma_kernel<4, 256, 1><<<ff_blocks, 256, 0, stream>>>(
        ffhbf, wtF1a, nullptr, nullptr, pooled, nullptr, NG, 0, 128, 0);
    gemm_mfma_kernel<4, 256, 2><<<ff_blocks, 256, 0, stream>>>(
        ffhbf, wtF1b, fb1, nullptr, out, pooled, NG, 128, 128, 0);
}

// Round 14
// 580.173 us; speedup vs baseline: 1.0316x; 1.0316x over previous
//
#include <hip/hip_runtime.h>

#define NN 400000
#define NE 800000
#define NG 16384

typedef short bf16x8 __attribute__((ext_vector_type(8)));
typedef float f32x4 __attribute__((ext_vector_type(4)));
typedef unsigned short u16x8 __attribute__((ext_vector_type(8)));

static inline int cdiv(int a, int b) { return (a + b - 1) / b; }

__device__ inline unsigned short bf16_rne(float v) {
    unsigned u = __float_as_uint(v);
    unsigned r = u + 0x7FFFu + ((u >> 16) & 1u);
    return (unsigned short)(r >> 16);
}
__device__ inline float bf16_to_f(unsigned short h) {
    return __uint_as_float(((unsigned)h) << 16);
}
__device__ inline void split2(float v, unsigned short& hi, unsigned short& lo) {
    hi = bf16_rne(v);
    lo = bf16_rne(v - bf16_to_f(hi));
}

__global__ __launch_bounds__(256) void fill_kernel(float* __restrict__ p, float v, int n) {
    int i = blockIdx.x * blockDim.x + threadIdx.x;
    if (i < n) p[i] = v;
}

// zero two int arrays in one launch
__global__ __launch_bounds__(256) void fill2_int_kernel(int* __restrict__ a,
                                                        int* __restrict__ b, int n) {
    int i = blockIdx.x * blockDim.x + threadIdx.x;
    if (i < n) a[i] = 0;
    else if (i < 2 * n) b[i - n] = 0;
}

__global__ __launch_bounds__(256) void hist_kernel(const int* __restrict__ dst,
                                                   int* __restrict__ deg, int E) {
    int e = blockIdx.x * blockDim.x + threadIdx.x;
    if (e < E) atomicAdd(&deg[dst[e]], 1);
}

__global__ __launch_bounds__(256) void disq_kernel(const int* __restrict__ deg,
                                                   float* __restrict__ disq, int n) {
    int i = blockIdx.x * blockDim.x + threadIdx.x;
    if (i < n) disq[i] = rsqrtf(1.0f + (float)deg[i]);
}

// ---- 3-pass exclusive scan ----
#define SCAN_TPB 256
#define SCAN_EPT 8
#define SCAN_BE (SCAN_TPB * SCAN_EPT)

__global__ __launch_bounds__(SCAN_TPB) void scan_a_kernel(const int* __restrict__ in,
                                                          int* __restrict__ out,
                                                          int* __restrict__ partials, int n) {
    __shared__ int sums[SCAN_TPB];
    const int tid = threadIdx.x;
    int base = blockIdx.x * SCAN_BE + tid * SCAN_EPT;
    int v[SCAN_EPT];
    int s = 0;
#pragma unroll
    for (int i = 0; i < SCAN_EPT; ++i) {
        int idx = base + i;
        int x = (idx < n) ? in[idx] : 0;
        v[i] = s;
        s += x;
    }
    sums[tid] = s;
    __syncthreads();
    for (int off = 1; off < SCAN_TPB; off <<= 1) {
        int t = (tid >= off) ? sums[tid - off] : 0;
        __syncthreads();
        sums[tid] += t;
        __syncthreads();
    }
    int toff = (tid == 0) ? 0 : sums[tid - 1];
#pragma unroll
    for (int i = 0; i < SCAN_EPT; ++i) {
        int idx = base + i;
        if (idx < n) out[idx] = toff + v[i];
    }
    if (tid == SCAN_TPB - 1) partials[blockIdx.x] = sums[SCAN_TPB - 1];
}

__global__ void scan_b_kernel(int* __restrict__ partials, int nb) {
    if (blockIdx.x == 0 && threadIdx.x == 0) {
        int s = 0;
        for (int i = 0; i < nb; ++i) { int x = partials[i]; partials[i] = s; s += x; }
    }
}

__global__ __launch_bounds__(256) void scan_c_kernel(int* __restrict__ out,
                                                     const int* __restrict__ partials, int n) {
    int idx = blockIdx.x * blockDim.x + threadIdx.x;
    if (idx < n) out[idx] += partials[idx / SCAN_BE];
}

// ---- CSR fill: entry = {src, norm_bits} packed ----
__global__ __launch_bounds__(256) void csr_fill_kernel(const int* __restrict__ src,
                                                       const int* __restrict__ dst,
                                                       const int* __restrict__ rowptr,
                                                       int* __restrict__ cnt,
                                                       const float* __restrict__ disq,
                                                       int2* __restrict__ csr_ent, int E) {
    int e = blockIdx.x * blockDim.x + threadIdx.x;
    if (e >= E) return;
    int d = dst[e], s = src[e];
    int pos = rowptr[d] + atomicAdd(&cnt[d], 1);
    csr_ent[pos] = make_int2(s, __float_as_int(disq[s] * disq[d]));
}

// ---- ALL weight preps in one launch: blockIdx.y selects the 128x128 slice.
// wt planes are contiguous: plane pair y at wtbase + y*2*128*128.
__global__ __launch_bounds__(256) void prep_w_all_kernel(const float* __restrict__ gW0,
                                                         const float* __restrict__ gW1,
                                                         const float* __restrict__ gW2,
                                                         const float* __restrict__ fW0,
                                                         const float* __restrict__ fW1,
                                                         unsigned short* __restrict__ wtbase) {
    int i = blockIdx.x * blockDim.x + threadIdx.x;
    if (i >= 128 * 128) return;
    const int y = blockIdx.y;
    const float* W;
    int Ktot, Ntot, k0, n0;
    switch (y) {
        case 0:  W = gW0; Ktot = 78;  Ntot = 128; k0 = 0;   n0 = 0;   break;
        case 1:  W = gW1; Ktot = 128; Ntot = 128; k0 = 0;   n0 = 0;   break;
        case 2:  W = gW2; Ktot = 128; Ntot = 128; k0 = 0;   n0 = 0;   break;
        case 3:  W = fW0; Ktot = 128; Ntot = 256; k0 = 0;   n0 = 0;   break;
        case 4:  W = fW0; Ktot = 128; Ntot = 256; k0 = 0;   n0 = 128; break;
        case 5:  W = fW1; Ktot = 256; Ntot = 128; k0 = 0;   n0 = 0;   break;
        default: W = fW1; Ktot = 256; Ntot = 128; k0 = 128; n0 = 0;   break;
    }
    unsigned short* planeHi = wtbase + (size_t)y * 2 * 128 * 128;
    unsigned short* planeLo = planeHi + 128 * 128;
    int n = i >> 7, k = i & 127;
    int gk = k0 + k, gn = n0 + n;
    float v = (gk < Ktot && gn < Ntot) ? W[(size_t)gk * Ntot + gn] : 0.0f;
    unsigned short hi, lo;
    split2(v, hi, lo);
    int elem = (n * 256 + ((2 * k) ^ ((n & 7) << 4))) >> 1;
    planeHi[elem] = hi;
    planeLo[elem] = lo;
}

// ---- x convert: [NN][78] fp32 -> bf16 hi-only [NN][96] (zero pad) ----
__global__ __launch_bounds__(256) void xconv_kernel(const float* __restrict__ x,
                                                    unsigned short* __restrict__ xbf) {
    int t = blockIdx.x * blockDim.x + threadIdx.x;
    if (t >= NN * 24) return;
    int node = t / 24;              // int32 magic-mul
    int q = (t - node * 24) * 4;    // 0,4,...,92
    const float* xp = x + (size_t)node * 78;
    ushort4 o;
    o.x = bf16_rne((q + 0 < 78) ? xp[q + 0] : 0.0f);
    o.y = bf16_rne((q + 1 < 78) ? xp[q + 1] : 0.0f);
    o.z = bf16_rne((q + 2 < 78) ? xp[q + 2] : 0.0f);
    o.w = bf16_rne((q + 3 < 78) ? xp[q + 3] : 0.0f);
    *reinterpret_cast<ushort4*>(xbf + (size_t)node * 96 + q) = o;
}

// ---- fp32 -> bf16 vector convert ----
__global__ __launch_bounds__(256) void f2bf_kernel(const float* __restrict__ in,
                                                   unsigned short* __restrict__ o, int n4) {
    int i = blockIdx.x * blockDim.x + threadIdx.x;
    if (i >= n4) return;
    float4 v = *reinterpret_cast<const float4*>(in + i * 4);
    ushort4 u;
    u.x = bf16_rne(v.x); u.y = bf16_rne(v.y); u.z = bf16_rne(v.z); u.w = bf16_rne(v.w);
    *reinterpret_cast<ushort4*>(o + i * 4) = u;
}

// ---- CSR gather over bf16 activations -> bf16 hi-only agg ----
// 8 lanes/node, 2x ushort8 (32B) per lane -> 8 independent node chains/wave.
// Per-column accumulation order identical to the 16-lane version (ascending
// edge index per column) -> bit-identical output. 4-edge predicated MLP.
template <int STRIDE>
__global__ __launch_bounds__(256) void gather_kernel(const unsigned short* __restrict__ act,
                                                     const int* __restrict__ rowptr,
                                                     const int* __restrict__ deg,
                                                     const int2* __restrict__ csr_ent,
                                                     const float* __restrict__ disq,
                                                     unsigned short* __restrict__ aggHi, int n) {
    int t = blockIdx.x * blockDim.x + threadIdx.x;
    if (t >= n * 8) return;
    int node = t >> 3, q = (t & 7) * 16;
    const bool live = q < STRIDE;
    const int qc = live ? q : 0;
    int beg = rowptr[node];
    int d = deg[node];
    float si = disq[node];
    float s2 = si * si;
    const unsigned short* sp = act + (size_t)node * STRIDE + qc;
    u16x8 sa = *reinterpret_cast<const u16x8*>(sp);
    u16x8 sb = *reinterpret_cast<const u16x8*>(sp + 8);
    float acc[16];
#pragma unroll
    for (int i = 0; i < 8; ++i) {
        acc[i]     = bf16_to_f(sa[i]) * s2;
        acc[8 + i] = bf16_to_f(sb[i]) * s2;
    }
    if (d > 0) {
        int lim = d - 1;
        int2 e[4];
        float nr[4];
#pragma unroll
        for (int j = 0; j < 4; ++j) e[j] = csr_ent[beg + (j < lim ? j : lim)];
#pragma unroll
        for (int j = 0; j < 4; ++j) nr[j] = (j < d) ? __int_as_float(e[j].y) : 0.0f;
        u16x8 ua[4], ub[4];
#pragma unroll
        for (int j = 0; j < 4; ++j) {
            const unsigned short* p = act + (size_t)e[j].x * STRIDE + qc;
            ua[j] = *reinterpret_cast<const u16x8*>(p);
            ub[j] = *reinterpret_cast<const u16x8*>(p + 8);
        }
#pragma unroll
        for (int j = 0; j < 4; ++j)
#pragma unroll
            for (int i = 0; i < 8; ++i) {
                acc[i]     = fmaf(bf16_to_f(ua[j][i]), nr[j], acc[i]);
                acc[8 + i] = fmaf(bf16_to_f(ub[j][i]), nr[j], acc[8 + i]);
            }
        for (int j = 4; j < d; ++j) {
            int2 ee = csr_ent[beg + j];
            float nn = __int_as_float(ee.y);
            const unsigned short* p = act + (size_t)ee.x * STRIDE + qc;
            u16x8 va = *reinterpret_cast<const u16x8*>(p);
            u16x8 vb = *reinterpret_cast<const u16x8*>(p + 8);
#pragma unroll
            for (int i = 0; i < 8; ++i) {
                acc[i]     = fmaf(bf16_to_f(va[i]), nn, acc[i]);
                acc[8 + i] = fmaf(bf16_to_f(vb[i]), nn, acc[8 + i]);
            }
        }
    }
    if (live) {
        u16x8 ha, hb;
#pragma unroll
        for (int i = 0; i < 8; ++i) {
            ha[i] = bf16_rne(acc[i]);
            hb[i] = bf16_rne(acc[8 + i]);
        }
        unsigned short* op = aggHi + (size_t)node * STRIDE + q;
        *reinterpret_cast<u16x8*>(op) = ha;
        *reinterpret_cast<u16x8*>(op + 8) = hb;
    }
}

// ---- bf16 MFMA GEMM, split weights (Whi+Wlo), 3 epilogue modes ----
// MODE 0: bf16 out = relu(acc + bias), row stride ostride, col offset ocol
// MODE 1: fp32 partial out (no bias/relu), stride 128
// MODE 2: fp32 out = relu(acc + partial + bias), stride 128
template <int NKC, int AS, int MODE>
__global__ __launch_bounds__(256) void gemm_mfma_kernel(const unsigned short* __restrict__ A,
                                                        const unsigned short* __restrict__ WT,
                                                        const float* __restrict__ bias,
                                                        unsigned short* __restrict__ actout,
                                                        float* __restrict__ f32out,
                                                        const float* __restrict__ partial,
                                                        int M, int a_k0, int ostride, int ocol) {
    __shared__ unsigned short lds[2 * 128 * 128];
    const int tid = threadIdx.x;
    {
        const unsigned* s = reinterpret_cast<const unsigned*>(WT);
        unsigned* d = reinterpret_cast<unsigned*>(lds);
#pragma unroll
        for (int i = 0; i < 64; ++i) d[tid + 256 * i] = s[tid + 256 * i];
    }
    __syncthreads();

    const int w = tid >> 6, lane = tid & 63;
    const int m = lane & 15, kb = lane >> 4;
    const char* ldsHiB = reinterpret_cast<const char*>(lds);
    const char* ldsLoB = ldsHiB + 128 * 256;

    float bcol[8];
    if (MODE != 1) {
#pragma unroll
        for (int ct = 0; ct < 8; ++ct) bcol[ct] = bias[ct * 16 + m];
    }

    const int RT = 4;
    for (int rt = 0; rt < RT; ++rt) {
        int row0 = (blockIdx.x * RT + rt) * 64;
        if (row0 >= M) return;
        int arow = row0 + w * 16 + m;

        bf16x8 ah[NKC];
#pragma unroll
        for (int kc = 0; kc < NKC; ++kc)
            ah[kc] = *reinterpret_cast<const bf16x8*>(A + (size_t)arow * AS + a_k0 + kc * 32 + kb * 8);

        f32x4 acc[8];
#pragma unroll
        for (int ct = 0; ct < 8; ++ct)
#pragma unroll
            for (int r = 0; r < 4; ++r) acc[ct][r] = 0.0f;

#pragma unroll
        for (int ct = 0; ct < 8; ++ct) {
            int n = ct * 16 + m;
            int swz = (n & 7) << 4;
            int rowb = n * 256;
#pragma unroll
            for (int kc = 0; kc < NKC; ++kc) {
                int bb = rowb + ((kc * 64 + kb * 16) ^ swz);
                bf16x8 bh = *reinterpret_cast<const bf16x8*>(ldsHiB + bb);
                bf16x8 bl = *reinterpret_cast<const bf16x8*>(ldsLoB + bb);
                acc[ct] = __builtin_amdgcn_mfma_f32_16x16x32_bf16(ah[kc], bh, acc[ct], 0, 0, 0);
                acc[ct] = __builtin_amdgcn_mfma_f32_16x16x32_bf16(ah[kc], bl, acc[ct], 0, 0, 0);
            }
        }

        // C/D: col = ct*16 + (lane&15), row = (lane>>4)*4 + r   [m89]
        if (MODE == 0) {
            unsigned short* ap = actout + (size_t)(row0 + w * 16) * ostride + ocol;
#pragma unroll
            for (int ct = 0; ct < 8; ++ct)
#pragma unroll
                for (int r = 0; r < 4; ++r) {
                    float v = fmaxf(acc[ct][r] + bcol[ct], 0.0f);
                    ap[(size_t)(kb * 4 + r) * ostride + ct * 16 + m] = bf16_rne(v);
                }
        } else if (MODE == 1) {
            float* fp = f32out + (size_t)(row0 + w * 16) * 128;
#pragma unroll
            for (int ct = 0; ct < 8; ++ct)
#pragma unroll
                for (int r = 0; r < 4; ++r)
                    fp[(size_t)(kb * 4 + r) * 128 + ct * 16 + m] = acc[ct][r];
        } else {
            const float* pp = partial + (size_t)(row0 + w * 16) * 128;
            float* fp = f32out + (size_t)(row0 + w * 16) * 128;
#pragma unroll
            for (int ct = 0; ct < 8; ++ct)
#pragma unroll
                for (int r = 0; r < 4; ++r) {
                    size_t idx = (size_t)(kb * 4 + r) * 128 + ct * 16 + m;
                    float v = fmaxf(acc[ct][r] + pp[idx] + bcol[ct], 0.0f);
                    fp[idx] = v;
                }
        }
    }
}

// batch sorted: pre-reduce runs of 8 nodes, flush on boundary. reads bf16 act.
__global__ __launch_bounds__(256) void pool_kernel(const unsigned short* __restrict__ act,
                                                   const int* __restrict__ batch,
                                                   int* __restrict__ pooled, int n) {
    int t = blockIdx.x * blockDim.x + threadIdx.x;
    int d = t & 127;
    int n0 = (t >> 7) * 8;
    if (n0 >= n) return;
    int cur = batch[n0];
    float m = fmaxf(bf16_to_f(act[(size_t)n0 * 128 + d]), 0.f);
    for (int i = 1; i < 8 && (n0 + i) < n; ++i) {
        int b = batch[n0 + i];
        float v = fmaxf(bf16_to_f(act[(size_t)(n0 + i) * 128 + d]), 0.f);
        if (b == cur) {
            m = fmaxf(m, v);
        } else {
            atomicMax(&pooled[cur * 128 + d], __float_as_int(m));
            cur = b;
            m = v;
        }
    }
    atomicMax(&pooled[cur * 128 + d], __float_as_int(m));
}

extern "C" void kernel_launch(void* const* d_in, const int* in_sizes, int n_in,
                              void* d_out, int out_size, void* d_ws, size_t ws_size,
                              hipStream_t stream) {
    const float* x    = (const float*)d_in[0];
    const int*   edge = (const int*)d_in[1];
    const int*   batch= (const int*)d_in[2];
    const float* gW0  = (const float*)d_in[4];
    const float* gb0  = (const float*)d_in[5];
    const float* gW1  = (const float*)d_in[6];
    const float* gb1  = (const float*)d_in[7];
    const float* gW2  = (const float*)d_in[8];
    const float* gb2  = (const float*)d_in[9];
    const float* fW0  = (const float*)d_in[10];
    const float* fb0  = (const float*)d_in[11];
    const float* fW1  = (const float*)d_in[12];
    const float* fb1  = (const float*)d_in[13];
    float* out = (float*)d_out;

    unsigned short* actB  = (unsigned short*)d_ws;            // NN*128 bf16 (aliases xbf NN*96)
    unsigned short* aggHi = actB + (size_t)NN * 128;          // NN*128 bf16
    float* disq   = (float*)(aggHi + (size_t)NN * 128);       // NN f32
    float* pooled = disq + NN;                                // NG*128 f32 (also FF1 partial)
    unsigned short* pooledbf = (unsigned short*)(pooled + (size_t)NG * 128);  // NG*128
    unsigned short* ffhbf    = pooledbf + (size_t)NG * 128;   // NG*256
    int*   deg    = (int*)(ffhbf + (size_t)NG * 256);         // NN
    int*   rowptr = deg + NN;                                 // NN
    int2*  csr_ent = (int2*)(rowptr + NN);                    // NE
    unsigned short* wtbase = (unsigned short*)(csr_ent + NE); // 7 plane-pairs, contiguous
    unsigned short* wt0   = wtbase;                           // 2*128*128 each
    unsigned short* wt1   = wt0 + 2 * 128 * 128;
    unsigned short* wt2   = wt1 + 2 * 128 * 128;
    unsigned short* wtF0a = wt2 + 2 * 128 * 128;
    unsigned short* wtF0b = wtF0a + 2 * 128 * 128;
    unsigned short* wtF1a = wtF0b + 2 * 128 * 128;
    unsigned short* wtF1b = wtF1a + 2 * 128 * 128;
    int* partials = (int*)(wtF1b + 2 * 128 * 128);            // ~200 ints
    int* cnt = (int*)pooled;                                  // dead before pool init
    unsigned short* xbf = actB;                               // [NN,96]; dead after gather0

    const int* src = edge;
    const int* dst = edge + NE;

    // ---- degree + disq + CSR build + weight prep + x convert ----
    fill2_int_kernel<<<cdiv(2 * NN, 256), 256, 0, stream>>>(deg, cnt, NN);
    hist_kernel<<<cdiv(NE, 256), 256, 0, stream>>>(dst, deg, NE);
    disq_kernel<<<cdiv(NN, 256), 256, 0, stream>>>(deg, disq, NN);
    int nsb = cdiv(NN, SCAN_BE);
    scan_a_kernel<<<nsb, SCAN_TPB, 0, stream>>>(deg, rowptr, partials, NN);
    scan_b_kernel<<<1, 64, 0, stream>>>(partials, nsb);
    scan_c_kernel<<<cdiv(NN, 256), 256, 0, stream>>>(rowptr, partials, NN);
    csr_fill_kernel<<<cdiv(NE, 256), 256, 0, stream>>>(src, dst, rowptr, cnt, disq,
                                                       csr_ent, NE);
    prep_w_all_kernel<<<dim3(64, 7), 256, 0, stream>>>(gW0, gW1, gW2, fW0, fW1, wtbase);
    xconv_kernel<<<cdiv(NN * 24, 256), 256, 0, stream>>>(x, xbf);

    const int gemm_blocks = cdiv(NN / 64, 4);
    const int gather_blocks = cdiv(NN * 8, 256);
    const int ff_blocks = NG / 256;

    // ---- layer 0: agg = A_hat x ; act = relu(agg@W0 + b0) ----
    gather_kernel<96><<<gather_blocks, 256, 0, stream>>>(xbf, rowptr, deg, csr_ent, disq,
                                                         aggHi, NN);
    gemm_mfma_kernel<3, 96, 0><<<gemm_blocks, 256, 0, stream>>>(
        aggHi, wt0, gb0, actB, nullptr, nullptr, NN, 0, 128, 0);
    // ---- layer 1 ----
    gather_kernel<128><<<gather_blocks, 256, 0, stream>>>(actB, rowptr, deg, csr_ent, disq,
                                                          aggHi, NN);
    gemm_mfma_kernel<4, 128, 0><<<gemm_blocks, 256, 0, stream>>>(
        aggHi, wt1, gb1, actB, nullptr, nullptr, NN, 0, 128, 0);
    // ---- layer 2 ----
    gather_kernel<128><<<gather_blocks, 256, 0, stream>>>(actB, rowptr, deg, csr_ent, disq,
                                                          aggHi, NN);
    gemm_mfma_kernel<4, 128, 0><<<gemm_blocks, 256, 0, stream>>>(
        aggHi, wt2, gb2, actB, nullptr, nullptr, NN, 0, 128, 0);

    // ---- global max pool ----
    fill_kernel<<<cdiv(NG * 128, 256), 256, 0, stream>>>(pooled, 0.0f, NG * 128);
    pool_kernel<<<cdiv(cdiv(NN, 8) * 128, 256), 256, 0, stream>>>(actB, batch, (int*)pooled, NN);
    f2bf_kernel<<<cdiv(NG * 32, 256), 256, 0, stream>>>(pooled, pooledbf, NG * 32);

    // ---- FF head (MFMA) ----
    gemm_mfma_kernel<4, 128, 0><<<ff_blocks, 256, 0, stream>>>(
        pooledbf, wtF0a, fb0, ffhbf, nullptr, nullptr, NG, 0, 256, 0);
    gemm_mfma_kernel<4, 128, 0><<<ff_blocks, 256, 0, stream>>>(
        pooledbf, wtF0b, fb0 + 128, ffhbf, nullptr, nullptr, NG, 0, 256, 128);
    gemm_mfma_kernel<4, 256, 1><<<ff_blocks, 256, 0, stream>>>(
        ffhbf, wtF1a, nullptr, nullptr, pooled, nullptr, NG, 0, 128, 0);
    gemm_mfma_kernel<4, 256, 2><<<ff_blocks, 256, 0, stream>>>(
        ffhbf, wtF1b, fb1, nullptr, out, pooled, NG, 128, 128, 0);
}

// Round 15
// 554.599 us; speedup vs baseline: 1.0792x; 1.0461x over previous
//
#include <hip/hip_runtime.h>

#define NN 400000
#define NE 800000
#define NG 16384

typedef short bf16x8 __attribute__((ext_vector_type(8)));
typedef float f32x4 __attribute__((ext_vector_type(4)));
typedef unsigned short u16x8 __attribute__((ext_vector_type(8)));

static inline int cdiv(int a, int b) { return (a + b - 1) / b; }

__device__ inline unsigned short bf16_rne(float v) {
    unsigned u = __float_as_uint(v);
    unsigned r = u + 0x7FFFu + ((u >> 16) & 1u);
    return (unsigned short)(r >> 16);
}
__device__ inline float bf16_to_f(unsigned short h) {
    return __uint_as_float(((unsigned)h) << 16);
}
__device__ inline void split2(float v, unsigned short& hi, unsigned short& lo) {
    hi = bf16_rne(v);
    lo = bf16_rne(v - bf16_to_f(hi));
}

__global__ __launch_bounds__(256) void fill_kernel(float* __restrict__ p, float v, int n) {
    int i = blockIdx.x * blockDim.x + threadIdx.x;
    if (i < n) p[i] = v;
}

// zero two int arrays in one launch
__global__ __launch_bounds__(256) void fill2_int_kernel(int* __restrict__ a,
                                                        int* __restrict__ b, int n) {
    int i = blockIdx.x * blockDim.x + threadIdx.x;
    if (i < n) a[i] = 0;
    else if (i < 2 * n) b[i - n] = 0;
}

__global__ __launch_bounds__(256) void hist_kernel(const int* __restrict__ dst,
                                                   int* __restrict__ deg, int E) {
    int e = blockIdx.x * blockDim.x + threadIdx.x;
    if (e < E) atomicAdd(&deg[dst[e]], 1);
}

// ---- 3-pass exclusive scan; pass A also computes disq = rsqrt(1+deg) ----
#define SCAN_TPB 256
#define SCAN_EPT 8
#define SCAN_BE (SCAN_TPB * SCAN_EPT)

__global__ __launch_bounds__(SCAN_TPB) void scan_a_kernel(const int* __restrict__ in,
                                                          int* __restrict__ out,
                                                          int* __restrict__ partials,
                                                          float* __restrict__ disq, int n) {
    __shared__ int sums[SCAN_TPB];
    const int tid = threadIdx.x;
    int base = blockIdx.x * SCAN_BE + tid * SCAN_EPT;
    int v[SCAN_EPT];
    int s = 0;
#pragma unroll
    for (int i = 0; i < SCAN_EPT; ++i) {
        int idx = base + i;
        int x = (idx < n) ? in[idx] : 0;
        if (idx < n) disq[idx] = rsqrtf(1.0f + (float)x);
        v[i] = s;
        s += x;
    }
    sums[tid] = s;
    __syncthreads();
    for (int off = 1; off < SCAN_TPB; off <<= 1) {
        int t = (tid >= off) ? sums[tid - off] : 0;
        __syncthreads();
        sums[tid] += t;
        __syncthreads();
    }
    int toff = (tid == 0) ? 0 : sums[tid - 1];
#pragma unroll
    for (int i = 0; i < SCAN_EPT; ++i) {
        int idx = base + i;
        if (idx < n) out[idx] = toff + v[i];
    }
    if (tid == SCAN_TPB - 1) partials[blockIdx.x] = sums[SCAN_TPB - 1];
}

__global__ void scan_b_kernel(int* __restrict__ partials, int nb) {
    if (blockIdx.x == 0 && threadIdx.x == 0) {
        int s = 0;
        for (int i = 0; i < nb; ++i) { int x = partials[i]; partials[i] = s; s += x; }
    }
}

__global__ __launch_bounds__(256) void scan_c_kernel(int* __restrict__ out,
                                                     const int* __restrict__ partials, int n) {
    int idx = blockIdx.x * blockDim.x + threadIdx.x;
    if (idx < n) out[idx] += partials[idx / SCAN_BE];
}

// ---- CSR fill: entry = {src, norm_bits} packed ----
__global__ __launch_bounds__(256) void csr_fill_kernel(const int* __restrict__ src,
                                                       const int* __restrict__ dst,
                                                       const int* __restrict__ rowptr,
                                                       int* __restrict__ cnt,
                                                       const float* __restrict__ disq,
                                                       int2* __restrict__ csr_ent, int E) {
    int e = blockIdx.x * blockDim.x + threadIdx.x;
    if (e >= E) return;
    int d = dst[e], s = src[e];
    int pos = rowptr[d] + atomicAdd(&cnt[d], 1);
    csr_ent[pos] = make_int2(s, __float_as_int(disq[s] * disq[d]));
}

// ---- ALL weight preps in one launch: blockIdx.y selects the 128x128 slice ----
__global__ __launch_bounds__(256) void prep_w_all_kernel(const float* __restrict__ gW0,
                                                         const float* __restrict__ gW1,
                                                         const float* __restrict__ gW2,
                                                         const float* __restrict__ fW0,
                                                         const float* __restrict__ fW1,
                                                         unsigned short* __restrict__ wtbase) {
    int i = blockIdx.x * blockDim.x + threadIdx.x;
    if (i >= 128 * 128) return;
    const int y = blockIdx.y;
    const float* W;
    int Ktot, Ntot, k0, n0;
    switch (y) {
        case 0:  W = gW0; Ktot = 78;  Ntot = 128; k0 = 0;   n0 = 0;   break;
        case 1:  W = gW1; Ktot = 128; Ntot = 128; k0 = 0;   n0 = 0;   break;
        case 2:  W = gW2; Ktot = 128; Ntot = 128; k0 = 0;   n0 = 0;   break;
        case 3:  W = fW0; Ktot = 128; Ntot = 256; k0 = 0;   n0 = 0;   break;
        case 4:  W = fW0; Ktot = 128; Ntot = 256; k0 = 0;   n0 = 128; break;
        case 5:  W = fW1; Ktot = 256; Ntot = 128; k0 = 0;   n0 = 0;   break;
        default: W = fW1; Ktot = 256; Ntot = 128; k0 = 128; n0 = 0;   break;
    }
    unsigned short* planeHi = wtbase + (size_t)y * 2 * 128 * 128;
    unsigned short* planeLo = planeHi + 128 * 128;
    int n = i >> 7, k = i & 127;
    int gk = k0 + k, gn = n0 + n;
    float v = (gk < Ktot && gn < Ntot) ? W[(size_t)gk * Ntot + gn] : 0.0f;
    unsigned short hi, lo;
    split2(v, hi, lo);
    int elem = (n * 256 + ((2 * k) ^ ((n & 7) << 4))) >> 1;
    planeHi[elem] = hi;
    planeLo[elem] = lo;
}

// ---- x convert: [NN][78] fp32 -> bf16 hi-only [NN][96] (zero pad) ----
// float2 loads (78 even, 8B alignment holds; pairs never straddle the edge).
__global__ __launch_bounds__(256) void xconv_kernel(const float* __restrict__ x,
                                                    unsigned short* __restrict__ xbf) {
    int t = blockIdx.x * blockDim.x + threadIdx.x;
    if (t >= NN * 24) return;
    int node = t / 24;              // int32 magic-mul
    int q = (t - node * 24) * 4;    // 0,4,...,92
    const float* xp = x + (size_t)node * 78;
    float2 a = (q + 1 < 78) ? *reinterpret_cast<const float2*>(xp + q)
                            : make_float2(0.0f, 0.0f);
    float2 b = (q + 3 < 78) ? *reinterpret_cast<const float2*>(xp + q + 2)
                            : make_float2(0.0f, 0.0f);
    ushort4 o;
    o.x = bf16_rne(a.x);
    o.y = bf16_rne(a.y);
    o.z = bf16_rne(b.x);
    o.w = bf16_rne(b.y);
    *reinterpret_cast<ushort4*>(xbf + (size_t)node * 96 + q) = o;
}

// ---- fp32 -> bf16 vector convert ----
__global__ __launch_bounds__(256) void f2bf_kernel(const float* __restrict__ in,
                                                   unsigned short* __restrict__ o, int n4) {
    int i = blockIdx.x * blockDim.x + threadIdx.x;
    if (i >= n4) return;
    float4 v = *reinterpret_cast<const float4*>(in + i * 4);
    ushort4 u;
    u.x = bf16_rne(v.x); u.y = bf16_rne(v.y); u.z = bf16_rne(v.z); u.w = bf16_rne(v.w);
    *reinterpret_cast<ushort4*>(o + i * 4) = u;
}

// ---- CSR gather over bf16 activations -> bf16 hi-only agg ----
// 8 lanes/node, 2x ushort8 (32B) per lane -> 8 independent node chains/wave.
template <int STRIDE>
__global__ __launch_bounds__(256) void gather_kernel(const unsigned short* __restrict__ act,
                                                     const int* __restrict__ rowptr,
                                                     const int* __restrict__ deg,
                                                     const int2* __restrict__ csr_ent,
                                                     const float* __restrict__ disq,
                                                     unsigned short* __restrict__ aggHi, int n) {
    int t = blockIdx.x * blockDim.x + threadIdx.x;
    if (t >= n * 8) return;
    int node = t >> 3, q = (t & 7) * 16;
    const bool live = q < STRIDE;
    const int qc = live ? q : 0;
    int beg = rowptr[node];
    int d = deg[node];
    float si = disq[node];
    float s2 = si * si;
    const unsigned short* sp = act + (size_t)node * STRIDE + qc;
    u16x8 sa = *reinterpret_cast<const u16x8*>(sp);
    u16x8 sb = *reinterpret_cast<const u16x8*>(sp + 8);
    float acc[16];
#pragma unroll
    for (int i = 0; i < 8; ++i) {
        acc[i]     = bf16_to_f(sa[i]) * s2;
        acc[8 + i] = bf16_to_f(sb[i]) * s2;
    }
    if (d > 0) {
        int lim = d - 1;
        int2 e[4];
        float nr[4];
#pragma unroll
        for (int j = 0; j < 4; ++j) e[j] = csr_ent[beg + (j < lim ? j : lim)];
#pragma unroll
        for (int j = 0; j < 4; ++j) nr[j] = (j < d) ? __int_as_float(e[j].y) : 0.0f;
        u16x8 ua[4], ub[4];
#pragma unroll
        for (int j = 0; j < 4; ++j) {
            const unsigned short* p = act + (size_t)e[j].x * STRIDE + qc;
            ua[j] = *reinterpret_cast<const u16x8*>(p);
            ub[j] = *reinterpret_cast<const u16x8*>(p + 8);
        }
#pragma unroll
        for (int j = 0; j < 4; ++j)
#pragma unroll
            for (int i = 0; i < 8; ++i) {
                acc[i]     = fmaf(bf16_to_f(ua[j][i]), nr[j], acc[i]);
                acc[8 + i] = fmaf(bf16_to_f(ub[j][i]), nr[j], acc[8 + i]);
            }
        for (int j = 4; j < d; ++j) {
            int2 ee = csr_ent[beg + j];
            float nn = __int_as_float(ee.y);
            const unsigned short* p = act + (size_t)ee.x * STRIDE + qc;
            u16x8 va = *reinterpret_cast<const u16x8*>(p);
            u16x8 vb = *reinterpret_cast<const u16x8*>(p + 8);
#pragma unroll
            for (int i = 0; i < 8; ++i) {
                acc[i]     = fmaf(bf16_to_f(va[i]), nn, acc[i]);
                acc[8 + i] = fmaf(bf16_to_f(vb[i]), nn, acc[8 + i]);
            }
        }
    }
    if (live) {
        u16x8 ha, hb;
#pragma unroll
        for (int i = 0; i < 8; ++i) {
            ha[i] = bf16_rne(acc[i]);
            hb[i] = bf16_rne(acc[8 + i]);
        }
        unsigned short* op = aggHi + (size_t)node * STRIDE + q;
        *reinterpret_cast<u16x8*>(op) = ha;
        *reinterpret_cast<u16x8*>(op + 8) = hb;
    }
}

// ---- bf16 MFMA GEMM, split weights (Whi+Wlo), bf16 relu epilogue ----
// blockIdx.y selects a weight plane-pair slice (for N=256 outputs in one
// launch): WT += y*2*128*128, bias += y*128, ocol += y*128. y=0 for GNN.
template <int NKC, int AS>
__global__ __launch_bounds__(256) void gemm_mfma_kernel(const unsigned short* __restrict__ A,
                                                        const unsigned short* __restrict__ WT,
                                                        const float* __restrict__ bias,
                                                        unsigned short* __restrict__ actout,
                                                        int M, int ostride, int ocol) {
    __shared__ unsigned short lds[2 * 128 * 128];
    const int tid = threadIdx.x;
    const unsigned short* WTp = WT + (size_t)blockIdx.y * 2 * 128 * 128;
    {
        const unsigned* s = reinterpret_cast<const unsigned*>(WTp);
        unsigned* d = reinterpret_cast<unsigned*>(lds);
#pragma unroll
        for (int i = 0; i < 64; ++i) d[tid + 256 * i] = s[tid + 256 * i];
    }
    __syncthreads();

    const int w = tid >> 6, lane = tid & 63;
    const int m = lane & 15, kb = lane >> 4;
    const char* ldsHiB = reinterpret_cast<const char*>(lds);
    const char* ldsLoB = ldsHiB + 128 * 256;

    float bcol[8];
#pragma unroll
    for (int ct = 0; ct < 8; ++ct) bcol[ct] = bias[blockIdx.y * 128 + ct * 16 + m];
    const int ocol2 = ocol + blockIdx.y * 128;

    const int RT = 4;
    for (int rt = 0; rt < RT; ++rt) {
        int row0 = (blockIdx.x * RT + rt) * 64;
        if (row0 >= M) return;
        int arow = row0 + w * 16 + m;

        bf16x8 ah[NKC];
#pragma unroll
        for (int kc = 0; kc < NKC; ++kc)
            ah[kc] = *reinterpret_cast<const bf16x8*>(A + (size_t)arow * AS + kc * 32 + kb * 8);

        f32x4 acc[8];
#pragma unroll
        for (int ct = 0; ct < 8; ++ct)
#pragma unroll
            for (int r = 0; r < 4; ++r) acc[ct][r] = 0.0f;

#pragma unroll
        for (int ct = 0; ct < 8; ++ct) {
            int n = ct * 16 + m;
            int swz = (n & 7) << 4;
            int rowb = n * 256;
#pragma unroll
            for (int kc = 0; kc < NKC; ++kc) {
                int bb = rowb + ((kc * 64 + kb * 16) ^ swz);
                bf16x8 bh = *reinterpret_cast<const bf16x8*>(ldsHiB + bb);
                bf16x8 bl = *reinterpret_cast<const bf16x8*>(ldsLoB + bb);
                acc[ct] = __builtin_amdgcn_mfma_f32_16x16x32_bf16(ah[kc], bh, acc[ct], 0, 0, 0);
                acc[ct] = __builtin_amdgcn_mfma_f32_16x16x32_bf16(ah[kc], bl, acc[ct], 0, 0, 0);
            }
        }

        // C/D: col = ct*16 + (lane&15), row = (lane>>4)*4 + r   [m89]
        unsigned short* ap = actout + (size_t)(row0 + w * 16) * ostride + ocol2;
#pragma unroll
        for (int ct = 0; ct < 8; ++ct)
#pragma unroll
            for (int r = 0; r < 4; ++r) {
                float v = fmaxf(acc[ct][r] + bcol[ct], 0.0f);
                ap[(size_t)(kb * 4 + r) * ostride + ct * 16 + m] = bf16_rne(v);
            }
    }
}

// ---- FF1 in one pass: out[NG,128] = relu(ffh[NG,256] @ (W+W') + fb1) ----
// All 4 weight planes (a-hi, a-lo, b-hi, b-lo = 128 KiB) staged in LDS.
__global__ __launch_bounds__(256) void ff1_kernel(const unsigned short* __restrict__ A,
                                                  const unsigned short* __restrict__ WT4,
                                                  const float* __restrict__ bias,
                                                  float* __restrict__ out, int M) {
    __shared__ unsigned short lds[4 * 128 * 128];  // 128 KiB
    const int tid = threadIdx.x;
    {
        const unsigned* s = reinterpret_cast<const unsigned*>(WT4);
        unsigned* d = reinterpret_cast<unsigned*>(lds);
#pragma unroll
        for (int i = 0; i < 128; ++i) d[tid + 256 * i] = s[tid + 256 * i];
    }
    __syncthreads();

    const int w = tid >> 6, lane = tid & 63;
    const int m = lane & 15, kb = lane >> 4;
    const char* ldsB = reinterpret_cast<const char*>(lds);

    float bcol[8];
#pragma unroll
    for (int ct = 0; ct < 8; ++ct) bcol[ct] = bias[ct * 16 + m];

    const int RT = 4;
    for (int rt = 0; rt < RT; ++rt) {
        int row0 = (blockIdx.x * RT + rt) * 64;
        if (row0 >= M) return;
        int arow = row0 + w * 16 + m;

        bf16x8 ah[8];
#pragma unroll
        for (int kc = 0; kc < 8; ++kc)
            ah[kc] = *reinterpret_cast<const bf16x8*>(A + (size_t)arow * 256 + kc * 32 + kb * 8);

        f32x4 acc[8];
#pragma unroll
        for (int ct = 0; ct < 8; ++ct)
#pragma unroll
            for (int r = 0; r < 4; ++r) acc[ct][r] = 0.0f;

#pragma unroll
        for (int ct = 0; ct < 8; ++ct) {
            int n = ct * 16 + m;
            int swz = (n & 7) << 4;
            int rowb = n * 256;
#pragma unroll
            for (int kc = 0; kc < 8; ++kc) {
                int half = kc >> 2, kcl = kc & 3;
                int bb = rowb + ((kcl * 64 + kb * 16) ^ swz);
                bf16x8 bh = *reinterpret_cast<const bf16x8*>(ldsB + half * 65536 + bb);
                bf16x8 bl = *reinterpret_cast<const bf16x8*>(ldsB + half * 65536 + 32768 + bb);
                acc[ct] = __builtin_amdgcn_mfma_f32_16x16x32_bf16(ah[kc], bh, acc[ct], 0, 0, 0);
                acc[ct] = __builtin_amdgcn_mfma_f32_16x16x32_bf16(ah[kc], bl, acc[ct], 0, 0, 0);
            }
        }

        float* fp = out + (size_t)(row0 + w * 16) * 128;
#pragma unroll
        for (int ct = 0; ct < 8; ++ct)
#pragma unroll
            for (int r = 0; r < 4; ++r)
                fp[(size_t)(kb * 4 + r) * 128 + ct * 16 + m] =
                    fmaxf(acc[ct][r] + bcol[ct], 0.0f);
    }
}

// batch sorted: pre-reduce runs of 8 nodes, flush on boundary.
// ushort2 per lane (2 columns) -> per-column math/atomics bit-identical.
__global__ __launch_bounds__(256) void pool_kernel(const unsigned short* __restrict__ act,
                                                   const int* __restrict__ batch,
                                                   int* __restrict__ pooled, int n) {
    int t = blockIdx.x * blockDim.x + threadIdx.x;
    int d2 = (t & 63) * 2;
    int n0 = (t >> 6) * 8;
    if (n0 >= n) return;
    int cur = batch[n0];
    ushort2 v0 = *reinterpret_cast<const ushort2*>(act + (size_t)n0 * 128 + d2);
    float m0 = fmaxf(bf16_to_f(v0.x), 0.f);
    float m1 = fmaxf(bf16_to_f(v0.y), 0.f);
    for (int i = 1; i < 8 && (n0 + i) < n; ++i) {
        int b = batch[n0 + i];
        ushort2 vi = *reinterpret_cast<const ushort2*>(act + (size_t)(n0 + i) * 128 + d2);
        float a0 = fmaxf(bf16_to_f(vi.x), 0.f);
        float a1 = fmaxf(bf16_to_f(vi.y), 0.f);
        if (b == cur) {
            m0 = fmaxf(m0, a0);
            m1 = fmaxf(m1, a1);
        } else {
            atomicMax(&pooled[cur * 128 + d2], __float_as_int(m0));
            atomicMax(&pooled[cur * 128 + d2 + 1], __float_as_int(m1));
            cur = b;
            m0 = a0;
            m1 = a1;
        }
    }
    atomicMax(&pooled[cur * 128 + d2], __float_as_int(m0));
    atomicMax(&pooled[cur * 128 + d2 + 1], __float_as_int(m1));
}

extern "C" void kernel_launch(void* const* d_in, const int* in_sizes, int n_in,
                              void* d_out, int out_size, void* d_ws, size_t ws_size,
                              hipStream_t stream) {
    const float* x    = (const float*)d_in[0];
    const int*   edge = (const int*)d_in[1];
    const int*   batch= (const int*)d_in[2];
    const float* gW0  = (const float*)d_in[4];
    const float* gb0  = (const float*)d_in[5];
    const float* gW1  = (const float*)d_in[6];
    const float* gb1  = (const float*)d_in[7];
    const float* gW2  = (const float*)d_in[8];
    const float* gb2  = (const float*)d_in[9];
    const float* fW0  = (const float*)d_in[10];
    const float* fb0  = (const float*)d_in[11];
    const float* fW1  = (const float*)d_in[12];
    const float* fb1  = (const float*)d_in[13];
    float* out = (float*)d_out;

    unsigned short* actB  = (unsigned short*)d_ws;            // NN*128 bf16 (aliases xbf NN*96)
    unsigned short* aggHi = actB + (size_t)NN * 128;          // NN*128 bf16
    float* disq   = (float*)(aggHi + (size_t)NN * 128);       // NN f32
    float* pooled = disq + NN;                                // NG*128 f32
    unsigned short* pooledbf = (unsigned short*)(pooled + (size_t)NG * 128);  // NG*128
    unsigned short* ffhbf    = pooledbf + (size_t)NG * 128;   // NG*256
    int*   deg    = (int*)(ffhbf + (size_t)NG * 256);         // NN
    int*   rowptr = deg + NN;                                 // NN
    int2*  csr_ent = (int2*)(rowptr + NN);                    // NE
    unsigned short* wtbase = (unsigned short*)(csr_ent + NE); // 7 plane-pairs, contiguous
    unsigned short* wt0   = wtbase;                           // 2*128*128 each
    unsigned short* wt1   = wt0 + 2 * 128 * 128;
    unsigned short* wt2   = wt1 + 2 * 128 * 128;
    unsigned short* wtF0  = wt2 + 2 * 128 * 128;              // slices 3,4 (N=256)
    unsigned short* wtF1  = wtF0 + 2 * 2 * 128 * 128;         // slices 5,6 (K=256, 4 planes)
    int* partials = (int*)(wtF1 + 2 * 2 * 128 * 128);         // ~200 ints
    int* cnt = (int*)pooled;                                  // dead before pool init
    unsigned short* xbf = actB;                               // [NN,96]; dead after gather0

    const int* src = edge;
    const int* dst = edge + NE;

    // ---- degree + disq + CSR build + weight prep + x convert ----
    fill2_int_kernel<<<cdiv(2 * NN, 256), 256, 0, stream>>>(deg, cnt, NN);
    hist_kernel<<<cdiv(NE, 256), 256, 0, stream>>>(dst, deg, NE);
    int nsb = cdiv(NN, SCAN_BE);
    scan_a_kernel<<<nsb, SCAN_TPB, 0, stream>>>(deg, rowptr, partials, disq, NN);
    scan_b_kernel<<<1, 64, 0, stream>>>(partials, nsb);
    scan_c_kernel<<<cdiv(NN, 256), 256, 0, stream>>>(rowptr, partials, NN);
    csr_fill_kernel<<<cdiv(NE, 256), 256, 0, stream>>>(src, dst, rowptr, cnt, disq,
                                                       csr_ent, NE);
    prep_w_all_kernel<<<dim3(64, 7), 256, 0, stream>>>(gW0, gW1, gW2, fW0, fW1, wtbase);
    xconv_kernel<<<cdiv(NN * 24, 256), 256, 0, stream>>>(x, xbf);

    const int gemm_blocks = cdiv(NN / 64, 4);
    const int gather_blocks = cdiv(NN * 8, 256);
    const int ff_blocks = NG / 256;

    // ---- layer 0: agg = A_hat x ; act = relu(agg@W0 + b0) ----
    gather_kernel<96><<<gather_blocks, 256, 0, stream>>>(xbf, rowptr, deg, csr_ent, disq,
                                                         aggHi, NN);
    gemm_mfma_kernel<3, 96><<<gemm_blocks, 256, 0, stream>>>(
        aggHi, wt0, gb0, actB, NN, 128, 0);
    // ---- layer 1 ----
    gather_kernel<128><<<gather_blocks, 256, 0, stream>>>(actB, rowptr, deg, csr_ent, disq,
                                                          aggHi, NN);
    gemm_mfma_kernel<4, 128><<<gemm_blocks, 256, 0, stream>>>(
        aggHi, wt1, gb1, actB, NN, 128, 0);
    // ---- layer 2 ----
    gather_kernel<128><<<gather_blocks, 256, 0, stream>>>(actB, rowptr, deg, csr_ent, disq,
                                                          aggHi, NN);
    gemm_mfma_kernel<4, 128><<<gemm_blocks, 256, 0, stream>>>(
        aggHi, wt2, gb2, actB, NN, 128, 0);

    // ---- global max pool ----
    fill_kernel<<<cdiv(NG * 128, 256), 256, 0, stream>>>(pooled, 0.0f, NG * 128);
    pool_kernel<<<cdiv(cdiv(NN, 8) * 64, 256), 256, 0, stream>>>(actB, batch, (int*)pooled, NN);
    f2bf_kernel<<<cdiv(NG * 32, 256), 256, 0, stream>>>(pooled, pooledbf, NG * 32);

    // ---- FF head: FF0 one dispatch (grid.y=2), FF1 one dispatch (128K LDS) ----
    gemm_mfma_kernel<4, 128><<<dim3(ff_blocks, 2), 256, 0, stream>>>(
        pooledbf, wtF0, fb0, ffhbf, NG, 256, 0);
    ff1_kernel<<<ff_blocks, 256, 0, stream>>>(ffhbf, wtF1, fb1, out, NG);
}